// Round 1
// baseline (107.494 us; speedup 1.0000x reference)
//
#include <hip/hip_runtime.h>

#define IMG_H 512
#define IMG_W 512
#define NB    8
#define TS    32            // output tile
#define RAD   5             // gaussian radius
#define ET    (TS + 2*RAD)  // 42: e-tile (needs +-5 around output)
#define HT    (TS + 4*RAD)  // 52: h-tile (needs +-10 around output)

__global__ __launch_bounds__(256) void marl_fused(
    const float* __restrict__ prob,
    const float* __restrict__ cmap,
    const float* __restrict__ hmap,
    float* __restrict__ out)
{
    __shared__ float A[HT][HT];     // h halo tile (preserved; reused for delta)
    __shared__ float Brow[HT][ET];  // row-conv scratch (reused for 2nd row conv)
    __shared__ float E[ET][ET];     // e = G*h - c (zero outside image)
    __shared__ float red[256];

    // normalized 1-D gaussian, sigma=2, ksize=11
    float w[11];
    {
        float s = 0.f;
#pragma unroll
        for (int i = 0; i < 11; ++i) {
            float ax = (float)i - 5.0f;
            w[i] = expf(-(ax * ax) * 0.125f);
            s += w[i];
        }
        float inv = 1.0f / s;
#pragma unroll
        for (int i = 0; i < 11; ++i) w[i] *= inv;
    }
    float w2 = 0.f;
#pragma unroll
    for (int i = 0; i < 11; ++i) w2 += w[i] * w[i];
    const float sumk2 = w2 * w2;   // sum(k^2) of 2-D kernel

    const int tid = threadIdx.x;
    const int x0  = blockIdx.x * TS;
    const int y0  = blockIdx.y * TS;
    const int b   = blockIdx.z;
    const size_t base = (size_t)b * IMG_H * IMG_W;

    // ---- load h halo tile: (y0-10 .. y0+41) x (x0-10 .. x0+41), zero pad ----
    for (int i = tid; i < HT * HT; i += 256) {
        int ly = i / HT, lx = i - ly * HT;
        int gy = y0 + ly - 2 * RAD;
        int gx = x0 + lx - 2 * RAD;
        float v = 0.f;
        if ((unsigned)gy < IMG_H && (unsigned)gx < IMG_W)
            v = hmap[base + (size_t)gy * IMG_W + gx];
        A[ly][lx] = v;
    }
    __syncthreads();

    // ---- row conv 1: 52 rows x 42 cols ----
    for (int i = tid; i < HT * ET; i += 256) {
        int ly = i / ET, lx = i - ly * ET;
        float acc = 0.f;
#pragma unroll
        for (int j = 0; j < 11; ++j) acc += w[j] * A[ly][lx + j];
        Brow[ly][lx] = acc;
    }
    __syncthreads();

    // ---- col conv 1 + subtract c -> e (ZERO outside image: cascaded-SAME) ----
    for (int i = tid; i < ET * ET; i += 256) {
        int r = i / ET, cc = i - r * ET;
        int gy = y0 + r - RAD;
        int gx = x0 + cc - RAD;
        float v = 0.f;
        if ((unsigned)gy < IMG_H && (unsigned)gx < IMG_W) {
            float acc = 0.f;
#pragma unroll
            for (int j = 0; j < 11; ++j) acc += w[j] * Brow[r + j][cc];
            v = acc - cmap[base + (size_t)gy * IMG_W + gx];
        }
        E[r][cc] = v;
    }
    __syncthreads();

    // ---- row conv 2: 42 rows x 32 cols (reuse Brow) ----
    for (int i = tid; i < ET * TS; i += 256) {
        int r = i / TS, cc = i - r * TS;
        float acc = 0.f;
#pragma unroll
        for (int j = 0; j < 11; ++j) acc += w[j] * E[r][cc + j];
        Brow[r][cc] = acc;
    }
    __syncthreads();

    // ---- col conv 2 -> corr, fused reward * log_prob, accumulate ----
    float partial = 0.f;
    for (int i = tid; i < TS * TS; i += 256) {
        int r = i / TS, cc = i - r * TS;
        float corr = 0.f;
#pragma unroll
        for (int j = 0; j < 11; ++j) corr += w[j] * Brow[r + j][cc];
        int gy = y0 + r, gx = x0 + cc;
        size_t gi = base + (size_t)gy * IMG_W + gx;
        float hv = A[r + 2 * RAD][cc + 2 * RAD];   // h at output pixel
        float pv = prob[gi];
        float logp = (hv > 0.5f) ? logf(pv + 1e-8f) : logf(1.0f - pv + 1e-8f);
        float delta = 1.0f - 2.0f * hv;            // +-1 exactly
        float reward = 2.0f * delta * corr + sumk2; // delta^2 == 1
        partial += reward * logp;
    }

    // ---- block reduction ----
    red[tid] = partial;
    __syncthreads();
    for (int s = 128; s > 0; s >>= 1) {
        if (tid < s) red[tid] += red[tid + s];
        __syncthreads();
    }
    if (tid == 0) atomicAdd(out, red[0] * -0.125f);  // loss = -sum / B
}

extern "C" void kernel_launch(void* const* d_in, const int* in_sizes, int n_in,
                              void* d_out, int out_size, void* d_ws, size_t ws_size,
                              hipStream_t stream) {
    const float* prob = (const float*)d_in[0];  // prob_map
    const float* cmap = (const float*)d_in[1];  // c
    const float* hmap = (const float*)d_in[2];  // h_sampled
    float* out = (float*)d_out;

    hipMemsetAsync(out, 0, sizeof(float), stream);

    dim3 grid(IMG_W / TS, IMG_H / TS, NB);  // 16 x 16 x 8 = 2048 blocks
    dim3 block(256);
    marl_fused<<<grid, block, 0, stream>>>(prob, cmap, hmap, out);
}

// Round 2
// 104.739 us; speedup vs baseline: 1.0263x; 1.0263x over previous
//
#include <hip/hip_runtime.h>

#define IMG_H 512
#define IMG_W 512
#define NB    8
#define TS    32
// A (h tile): 52 rows (gy=y0-10..y0+41) x 56 cols (gx=x0-12..x0+43), stride 56
#define AROWS 52
#define ASTR  56
// Brow (row-conv1 out): 52 rows x 44 cols (bc: gx=x0-7+bc), stride 44
#define BROWS 52
#define BSTR  44
// E: 42x42 (er: gy=y0-5+er, ec: gx=x0-5+ec), stride 44, overlays A
#define ESTR  44
// Brow2 (row-conv2 out): 42 rows x 32 cols, stride 36, overlays Brow
#define B2STR 36

#define CONV11(p) (w[0]*(p)[0] + w[1]*(p)[1] + w[2]*(p)[2] + w[3]*(p)[3] + w[4]*(p)[4] \
                 + w[5]*(p)[5] + w[6]*(p)[6] + w[7]*(p)[7] + w[8]*(p)[8] + w[9]*(p)[9] \
                 + w[10]*(p)[10])

__global__ __launch_bounds__(256, 6) void marl_fused(
    const float* __restrict__ prob,
    const float* __restrict__ cmap,
    const float* __restrict__ hmap,
    float* __restrict__ out)
{
    __shared__ __align__(16) float Abuf[AROWS * ASTR];  // 2912 f, reused as E
    __shared__ __align__(16) float Bbuf[BROWS * BSTR];  // 2288 f, reused as Brow2
    __shared__ float red[4];

    // normalized 1-D gaussian, sigma=2, ksize=11
    float w[11];
    {
        float s = 0.f;
#pragma unroll
        for (int i = 0; i < 11; ++i) {
            float ax = (float)i - 5.0f;
            w[i] = expf(-(ax * ax) * 0.125f);
            s += w[i];
        }
        float inv = 1.0f / s;
#pragma unroll
        for (int i = 0; i < 11; ++i) w[i] *= inv;
    }
    float w2 = 0.f;
#pragma unroll
    for (int i = 0; i < 11; ++i) w2 += w[i] * w[i];
    const float sumk2 = w2 * w2;

    const int tid = threadIdx.x;
    const int x0  = blockIdx.x * TS;
    const int y0  = blockIdx.y * TS;
    const size_t base = (size_t)blockIdx.z * (IMG_H * IMG_W);

    // ---- phase 0: load h tile (52 x 56) via float4, zero-pad OOB ----
    for (int t = tid; t < AROWS * 14; t += 256) {
        int row = t / 14, q = t - row * 14;
        int gy  = y0 - 10 + row;
        int gx0 = x0 - 12 + 4 * q;
        float4 v;
        if ((unsigned)gy < IMG_H && gx0 >= 0 && gx0 + 3 < IMG_W) {
            v = *reinterpret_cast<const float4*>(&hmap[base + (size_t)gy * IMG_W + gx0]);
        } else {
            const float* hr = &hmap[base + (size_t)gy * IMG_W];
            bool yin = (unsigned)gy < IMG_H;
            v.x = (yin && (unsigned)(gx0 + 0) < IMG_W) ? hr[gx0 + 0] : 0.f;
            v.y = (yin && (unsigned)(gx0 + 1) < IMG_W) ? hr[gx0 + 1] : 0.f;
            v.z = (yin && (unsigned)(gx0 + 2) < IMG_W) ? hr[gx0 + 2] : 0.f;
            v.w = (yin && (unsigned)(gx0 + 3) < IMG_W) ? hr[gx0 + 3] : 0.f;
        }
        *reinterpret_cast<float4*>(&Abuf[row * ASTR + 4 * q]) = v;
    }
    __syncthreads();

    // ---- phase 1: row conv1, 52 rows x 44 out cols, 4 outs/thread ----
    // out col bc <-> gx = x0-7+bc; taps A cols bc..bc+10
    for (int t = tid; t < BROWS * 11; t += 256) {
        int row = t / 11, grp = t - row * 11;
        int bc0 = 4 * grp;
        const float* src = &Abuf[row * ASTR + bc0];
        float win[16];
        *reinterpret_cast<float4*>(&win[0])  = *reinterpret_cast<const float4*>(&src[0]);
        *reinterpret_cast<float4*>(&win[4])  = *reinterpret_cast<const float4*>(&src[4]);
        *reinterpret_cast<float4*>(&win[8])  = *reinterpret_cast<const float4*>(&src[8]);
        *reinterpret_cast<float4*>(&win[12]) = *reinterpret_cast<const float4*>(&src[12]);
        float4 o;
        o.x = CONV11(win + 0);
        o.y = CONV11(win + 1);
        o.z = CONV11(win + 2);
        o.w = CONV11(win + 3);
        *reinterpret_cast<float4*>(&Bbuf[row * BSTR + bc0]) = o;
    }
    __syncthreads();

    // ---- phase 2: col conv1 + c subtract -> E (42x42), 7 outs/thread ----
    // E[er][ec]: gy = y0-5+er, gx = x0-5+ec; taps Brow rows er..er+10, col ec+2
    float* Ebuf = Abuf;
    {
        int t = tid;
        if (t < 252) {
            int g = t / 42, col = t - g * 42;
            int er0 = 7 * g;
            int bc  = col + 2;
            float win[17];
#pragma unroll
            for (int i = 0; i < 17; ++i) win[i] = Bbuf[(er0 + i) * BSTR + bc];
            int  gx  = x0 - 5 + col;
            bool xin = (unsigned)gx < IMG_W;
#pragma unroll
            for (int k = 0; k < 7; ++k) {
                int er = er0 + k;
                int gy = y0 - 5 + er;
                float v = 0.f;
                if (xin && (unsigned)gy < IMG_H) {
                    float acc = CONV11(win + k);
                    v = acc - cmap[base + (size_t)gy * IMG_W + gx];
                }
                Ebuf[er * ESTR + col] = v;
            }
        }
    }
    __syncthreads();

    // ---- phase 3: row conv2, 42 rows x 32 cols, 4 outs/thread ----
    // Brow2[er][cc]: gx = x0+cc; taps E cols cc..cc+10
    for (int t = tid; t < 336; t += 256) {
        int grp = t / 42, row = t - grp * 42;
        int cc0 = 4 * grp;
        const float* src = &Ebuf[row * ESTR + cc0];
        float win[16];
        *reinterpret_cast<float4*>(&win[0])  = *reinterpret_cast<const float4*>(&src[0]);
        *reinterpret_cast<float4*>(&win[4])  = *reinterpret_cast<const float4*>(&src[4]);
        *reinterpret_cast<float4*>(&win[8])  = *reinterpret_cast<const float4*>(&src[8]);
        *reinterpret_cast<float4*>(&win[12]) = *reinterpret_cast<const float4*>(&src[12]);
        float4 o;
        o.x = CONV11(win + 0);
        o.y = CONV11(win + 1);
        o.z = CONV11(win + 2);
        o.w = CONV11(win + 3);
        *reinterpret_cast<float4*>(&Bbuf[row * B2STR + cc0]) = o;
    }
    __syncthreads();

    // ---- phase 4: col conv2 -> corr + reward*logp, 4 outs/thread ----
    float partial = 0.f;
    {
        int ox  = tid & 31;
        int g   = tid >> 5;     // 0..7
        int oy0 = 4 * g;
        float win[14];
#pragma unroll
        for (int i = 0; i < 14; ++i) win[i] = Bbuf[(oy0 + i) * B2STR + ox];
#pragma unroll
        for (int k = 0; k < 4; ++k) {
            float corr = CONV11(win + k);
            int gy = y0 + oy0 + k;
            size_t gi = base + (size_t)gy * IMG_W + (x0 + ox);
            float hv = hmap[gi];
            float pv = prob[gi];
            float logp = (hv > 0.5f) ? logf(pv + 1e-8f) : logf(1.0f - pv + 1e-8f);
            float delta = 1.0f - 2.0f * hv;
            partial += (2.0f * delta * corr + sumk2) * logp;
        }
    }

    // ---- reduction: wave shuffle + tiny LDS ----
#pragma unroll
    for (int off = 32; off > 0; off >>= 1)
        partial += __shfl_down(partial, off, 64);
    if ((tid & 63) == 0) red[tid >> 6] = partial;
    __syncthreads();
    if (tid == 0) {
        float s = red[0] + red[1] + red[2] + red[3];
        atomicAdd(out, s * -0.125f);   // loss = -sum / B
    }
}

extern "C" void kernel_launch(void* const* d_in, const int* in_sizes, int n_in,
                              void* d_out, int out_size, void* d_ws, size_t ws_size,
                              hipStream_t stream) {
    const float* prob = (const float*)d_in[0];
    const float* cmap = (const float*)d_in[1];
    const float* hmap = (const float*)d_in[2];
    float* out = (float*)d_out;

    hipMemsetAsync(out, 0, sizeof(float), stream);

    dim3 grid(IMG_W / TS, IMG_H / TS, NB);  // 16 x 16 x 8
    dim3 block(256);
    marl_fused<<<grid, block, 0, stream>>>(prob, cmap, hmap, out);
}